// Round 2
// baseline (1032.045 us; speedup 1.0000x reference)
//
#include <hip/hip_runtime.h>
#include <hip/hip_bf16.h>
#include <cmath>

// out[b] = X_b (Wq Wk^T) (X_b^T X_b) / 768^1.5
// Factorized: P = Wq Wk^T (once), G_b = X^T X, H_b = scale * P G_b, out_b = X H_b.
// 47 GF total vs 141 GF naive; no S*S intermediate.
// Inputs/outputs are fp32 (per the reference); all accumulation fp32.

#define BMt 64
#define BNt 64
#define BKt 16
#define PAD 4   // keeps float4 row alignment (68*4=272B, 16B-aligned); 2-way bank aliasing is free

// C[M,N] = alpha * op(A) * op(B); op per TA/TB. Row-major, batched via blockIdx.z strides.
// TA: element (m,k) at A[k*lda + m]   (A = X^T with X row-major)
// TB: element (k,n) at B[n*ldb + k]   (B = W^T with W row-major)
template <bool TA, bool TB>
__global__ __launch_bounds__(256)
void gemm_tiled(const float* __restrict__ Ab, const float* __restrict__ Bb,
                float* __restrict__ Cb, int M, int N, int K,
                int lda, int ldb, int ldc,
                long sA, long sB, long sC, float alpha)
{
    const float* A  = Ab + (long)blockIdx.z * sA;
    const float* Bm = Bb + (long)blockIdx.z * sB;
    float* C        = Cb + (long)blockIdx.z * sC;

    __shared__ float As[BKt][BMt + PAD];
    __shared__ float Bs[BKt][BNt + PAD];

    const int tid = threadIdx.x;
    const int tx = tid & 15;   // 16 col-groups
    const int ty = tid >> 4;   // 16 row-groups
    const int rowBase = blockIdx.x * BMt;
    const int colBase = blockIdx.y * BNt;

    float acc[4][4] = {};

    for (int k0 = 0; k0 < K; k0 += BKt) {
        // ---- stage A tile (loop mapping chosen so global reads are coalesced) ----
        if (TA) {
            // element (m,k) at A[k*lda+m]: m fast in memory
            for (int i = tid; i < BKt * BMt; i += 256) {
                int kk = i >> 6, mm = i & 63;
                As[kk][mm] = A[(long)(k0 + kk) * lda + (rowBase + mm)];
            }
        } else {
            // element (m,k) at A[m*lda+k]: k fast in memory
            for (int i = tid; i < BKt * BMt; i += 256) {
                int kk = i & 15, mm = i >> 4;
                As[kk][mm] = A[(long)(rowBase + mm) * lda + (k0 + kk)];
            }
        }
        // ---- stage B tile ----
        if (!TB) {
            for (int i = tid; i < BKt * BNt; i += 256) {
                int kk = i >> 6, nn = i & 63;
                Bs[kk][nn] = Bm[(long)(k0 + kk) * ldb + (colBase + nn)];
            }
        } else {
            for (int i = tid; i < BKt * BNt; i += 256) {
                int kk = i & 15, nn = i >> 4;
                Bs[kk][nn] = Bm[(long)(colBase + nn) * ldb + (k0 + kk)];
            }
        }
        __syncthreads();

        #pragma unroll
        for (int kk = 0; kk < BKt; ++kk) {
            float4 a4 = *reinterpret_cast<const float4*>(&As[kk][ty * 4]);
            float4 b4 = *reinterpret_cast<const float4*>(&Bs[kk][tx * 4]);
            float av[4] = {a4.x, a4.y, a4.z, a4.w};
            float bv[4] = {b4.x, b4.y, b4.z, b4.w};
            #pragma unroll
            for (int i = 0; i < 4; ++i)
                #pragma unroll
                for (int j = 0; j < 4; ++j)
                    acc[i][j] += av[i] * bv[j];
        }
        __syncthreads();
    }

    // All problem dims are multiples of 64 -> no bounds checks needed.
    #pragma unroll
    for (int i = 0; i < 4; ++i) {
        long gm = rowBase + ty * 4 + i;
        #pragma unroll
        for (int j = 0; j < 4; ++j) {
            long gn = colBase + tx * 4 + j;
            C[gm * ldc + gn] = alpha * acc[i][j];
        }
    }
}

extern "C" void kernel_launch(void* const* d_in, const int* in_sizes, int n_in,
                              void* d_out, int out_size, void* d_ws, size_t ws_size,
                              hipStream_t stream)
{
    const float* X  = (const float*)d_in[0];  // [8,2048,768] fp32
    // d_in[1] attention_mask (int32): dead code in the reference output
    const float* Wq = (const float*)d_in[2];  // [768,768] fp32
    const float* Wk = (const float*)d_in[3];  // [768,768] fp32
    // d_in[4] Wv: dead
    float* out = (float*)d_out;               // [8,2048,768] fp32

    const int Bn = 8, S = 2048, D = 768;

    // fp32 scratch layout in d_ws: P[D*D] | G[B*D*D] | H[B*D*D]  (~40.2 MB)
    float* P = (float*)d_ws;
    float* G = P + (size_t)D * D;
    float* H = G + (size_t)Bn * D * D;

    const float alpha = 1.0f / (768.0f * sqrtf(768.0f));  // 1/768^1.5

    dim3 blk(256);

    // P = Wq * Wk^T            (NT, M=N=K=768)
    gemm_tiled<false, true><<<dim3(D / 64, D / 64, 1), blk, 0, stream>>>(
        Wq, Wk, P, D, D, D, D, D, D, 0L, 0L, 0L, 1.0f);

    // G[b] = X^T * X           (TN, M=N=768, K=2048)
    gemm_tiled<true, false><<<dim3(D / 64, D / 64, Bn), blk, 0, stream>>>(
        X, X, G, D, D, S, D, D, D, (long)S * D, (long)S * D, (long)D * D, 1.0f);

    // H[b] = alpha * P * G[b]  (NN, M=N=K=768)
    gemm_tiled<false, false><<<dim3(D / 64, D / 64, Bn), blk, 0, stream>>>(
        P, G, H, D, D, D, D, D, D, 0L, (long)D * D, (long)D * D, alpha);

    // out[b] = X * H[b]        (NN, M=2048, N=K=768)
    gemm_tiled<false, false><<<dim3(S / 64, D / 64, Bn), blk, 0, stream>>>(
        X, H, out, S, D, D, D, D, D, (long)S * D, (long)D * D, (long)S * D, 1.0f);
}

// Round 3
// 258.787 us; speedup vs baseline: 3.9880x; 3.9880x over previous
//
#include <hip/hip_runtime.h>
#include <hip/hip_bf16.h>
#include <cmath>

// out[b] = X_b (Wq Wk^T) (X_b^T X_b) / 768^1.5
// Factorized (47 GF vs 141 GF naive), all products in C = A*B^T form:
//   P  = Wq * Wk^T                    (fp32 sources, bf16 out)
//   G_b = Xt_b * Xt_b^T               (Xt = X^T, bf16; G symmetric)
//   Ht_b = alpha * G_b * P^T          (== H^T since G symmetric; bf16 out)
//   out_b = X_b * Ht_b^T              (fp32 A, fp32 out)
// MFMA bf16 16x16x32, 128x128 tile, BK=32, fp32 accumulate.

typedef __attribute__((ext_vector_type(8))) short short8;
typedef __attribute__((ext_vector_type(4))) float f32x4;

__device__ __forceinline__ unsigned short f2bf(float f) {
    union { float f; unsigned int u; } v; v.f = f;
    unsigned int u = v.u;
    return (unsigned short)((u + 0x7FFFu + ((u >> 16) & 1u)) >> 16);  // RNE
}

// ---- transpose + bf16 convert: X[b][S][D] (fp32) -> Xt[b][D][S] (bf16) ----
__global__ __launch_bounds__(256)
void transpose_bf16(const float* __restrict__ X, unsigned short* __restrict__ Xt,
                    int S, int D)
{
    __shared__ unsigned short tile[32][33];
    const int b = blockIdx.z;
    const int s0 = blockIdx.x * 32;
    const int d0 = blockIdx.y * 32;
    const float* Xb = X + (size_t)b * S * D;
    unsigned short* Xtb = Xt + (size_t)b * S * D;
    const int tx = threadIdx.x & 31;
    const int ty = threadIdx.x >> 5;  // 0..7
    #pragma unroll
    for (int i = 0; i < 4; ++i) {
        int s = ty * 4 + i;
        tile[s][tx] = f2bf(Xb[(size_t)(s0 + s) * D + d0 + tx]);
    }
    __syncthreads();
    #pragma unroll
    for (int i = 0; i < 4; ++i) {
        int d = ty * 4 + i;
        Xtb[(size_t)(d0 + d) * S + s0 + tx] = tile[tx][d];
    }
}

// ---- staging: 128x32 tile of A (row-major, ld = K) into LDS bf16 [128][32] ----
__device__ __forceinline__ void stage_tile(const float* src, unsigned short* lds, int ld, int tid)
{
    #pragma unroll
    for (int it = 0; it < 4; ++it) {
        int idx = it * 256 + tid;         // 0..1023
        int r = idx >> 3;                 // 8 threads per row
        int c = (idx & 7) * 4;
        float4 v = *reinterpret_cast<const float4*>(&src[(size_t)r * ld + c]);
        unsigned long long p =
            (unsigned long long)f2bf(v.x)         |
            ((unsigned long long)f2bf(v.y) << 16) |
            ((unsigned long long)f2bf(v.z) << 32) |
            ((unsigned long long)f2bf(v.w) << 48);
        *reinterpret_cast<unsigned long long*>(&lds[r * 32 + c]) = p;
    }
}
__device__ __forceinline__ void stage_tile(const unsigned short* src, unsigned short* lds, int ld, int tid)
{
    #pragma unroll
    for (int it = 0; it < 2; ++it) {
        int idx = it * 256 + tid;         // 0..511
        int r = idx >> 2;                 // 4 threads per row
        int c = (idx & 3) * 8;
        uint4 v = *reinterpret_cast<const uint4*>(&src[(size_t)r * ld + c]);
        *reinterpret_cast<uint4*>(&lds[r * 32 + c]) = v;
    }
}

__device__ __forceinline__ void store_c(float* C, size_t i, float v) { C[i] = v; }
__device__ __forceinline__ void store_c(unsigned short* C, size_t i, float v) { C[i] = f2bf(v); }

// C[M,N] = alpha * A[M,K] * Bt[N,K]^T ; all row-major, batched via blockIdx.z.
template <typename AT, typename BT, typename CT>
__global__ __launch_bounds__(256)
void gemm_abt(const AT* __restrict__ Ab, const BT* __restrict__ Bb,
              CT* __restrict__ Cb, int M, int N, int K,
              long sA, long sB, long sC, float alpha)
{
    const AT* A  = Ab + (long)blockIdx.z * sA;
    const BT* Bt = Bb + (long)blockIdx.z * sB;
    CT* C        = Cb + (long)blockIdx.z * sC;

    __shared__ unsigned short Alds[128 * 32];
    __shared__ unsigned short Blds[128 * 32];

    const int tid  = threadIdx.x;
    const int lane = tid & 63;
    const int wave = tid >> 6;            // 0..3
    const int wr   = (wave >> 1) * 64;    // wave row quadrant
    const int wc   = (wave & 1) * 64;     // wave col quadrant
    const int rowBase = blockIdx.x * 128;
    const int colBase = blockIdx.y * 128;
    const int l15  = lane & 15;
    const int quad = lane >> 4;

    f32x4 acc[4][4] = {};

    for (int k0 = 0; k0 < K; k0 += 32) {
        stage_tile(A  + (size_t)rowBase * K + k0, Alds, K, tid);
        stage_tile(Bt + (size_t)colBase * K + k0, Blds, K, tid);
        __syncthreads();

        short8 af[4], bfr[4];
        #pragma unroll
        for (int i = 0; i < 4; ++i) {
            af[i]  = *reinterpret_cast<const short8*>(&Alds[(wr + i * 16 + l15) * 32 + quad * 8]);
            bfr[i] = *reinterpret_cast<const short8*>(&Blds[(wc + i * 16 + l15) * 32 + quad * 8]);
        }
        #pragma unroll
        for (int mi = 0; mi < 4; ++mi)
            #pragma unroll
            for (int ni = 0; ni < 4; ++ni)
                acc[mi][ni] = __builtin_amdgcn_mfma_f32_16x16x32_bf16(
                    af[mi], bfr[ni], acc[mi][ni], 0, 0, 0);
        __syncthreads();
    }

    // C/D layout (m89-verified): col = lane&15, row = quad*4 + reg
    #pragma unroll
    for (int mi = 0; mi < 4; ++mi) {
        #pragma unroll
        for (int ni = 0; ni < 4; ++ni) {
            int col = colBase + wc + ni * 16 + l15;
            #pragma unroll
            for (int r = 0; r < 4; ++r) {
                int row = rowBase + wr + mi * 16 + quad * 4 + r;
                store_c(C, (size_t)row * N + col, alpha * acc[mi][ni][r]);
            }
        }
    }
}

extern "C" void kernel_launch(void* const* d_in, const int* in_sizes, int n_in,
                              void* d_out, int out_size, void* d_ws, size_t ws_size,
                              hipStream_t stream)
{
    const float* X  = (const float*)d_in[0];  // [8,2048,768] fp32
    const float* Wq = (const float*)d_in[2];  // [768,768]
    const float* Wk = (const float*)d_in[3];  // [768,768]
    float* out = (float*)d_out;               // [8,2048,768] fp32

    const int Bn = 8, S = 2048, D = 768;

    // bf16 workspace: Xt | P | G | Ht  (~45 MB)
    unsigned short* Xt16 = (unsigned short*)d_ws;            // [8][768][2048]
    unsigned short* P16  = Xt16 + (size_t)Bn * S * D;        // [768][768]
    unsigned short* G16  = P16  + (size_t)D * D;             // [8][768][768]
    unsigned short* Ht16 = G16  + (size_t)Bn * D * D;        // [8][768][768]

    const float alpha = 1.0f / (768.0f * sqrtf(768.0f));     // 1/768^1.5

    // Xt_b = X_b^T (bf16)
    transpose_bf16<<<dim3(S / 32, D / 32, Bn), 256, 0, stream>>>(X, Xt16, S, D);

    // P = Wq * Wk^T   (fp32 in, bf16 out)
    gemm_abt<float, float, unsigned short>
        <<<dim3(6, 6, 1), 256, 0, stream>>>(Wq, Wk, P16, D, D, D, 0L, 0L, 0L, 1.0f);

    // G_b = Xt_b * Xt_b^T   (K = 2048)
    gemm_abt<unsigned short, unsigned short, unsigned short>
        <<<dim3(6, 6, Bn), 256, 0, stream>>>(Xt16, Xt16, G16, D, D, S,
                                             (long)D * S, (long)D * S, (long)D * D, 1.0f);

    // Ht_b = alpha * G_b * P^T   (G symmetric => this is H^T)
    gemm_abt<unsigned short, unsigned short, unsigned short>
        <<<dim3(6, 6, Bn), 256, 0, stream>>>(G16, P16, Ht16, D, D, D,
                                             (long)D * D, 0L, (long)D * D, alpha);

    // out_b = X_b * Ht_b^T   (fp32 A converted in staging, fp32 out)
    gemm_abt<float, unsigned short, float>
        <<<dim3(S / 128, 6, Bn), 256, 0, stream>>>(X, Ht16, out, S, D, D,
                                                   (long)S * D, (long)D * D, (long)S * D, 1.0f);
}